// Round 11
// baseline (119.800 us; speedup 1.0000x reference)
//
#include <hip/hip_runtime.h>
#include <hip/hip_bf16.h>
#include <math.h>

typedef __attribute__((ext_vector_type(8))) short short8;
typedef __attribute__((ext_vector_type(4))) float floatx4;

#define MARGIN_C    0.09f
#define ONE_M_EPS   0.99999f
#define NCLS        64
#define MEMSTRIDE   256

__device__ __forceinline__ unsigned short f2bf(float f) {
    unsigned u = __float_as_uint(f);
    u += 0x7fffu + ((u >> 16) & 1u);
    return (unsigned short)(u >> 16);
}
__device__ __forceinline__ float bf2f(unsigned short v) {
    return __uint_as_float(((unsigned)v) << 16);
}
// order-preserving float<->uint key for atomicMax on floats
__device__ __forceinline__ unsigned fkey(float f) {
    unsigned u = __float_as_uint(f);
    return (u >> 31) ? ~u : (u | 0x80000000u);
}
__device__ __forceinline__ float fdec(unsigned k) {
    return __uint_as_float((k >> 31) ? (k & 0x7fffffffu) : ~k);
}
__device__ __forceinline__ void gld16(const void* g, void* l) {
    __builtin_amdgcn_global_load_lds(
        (const __attribute__((address_space(1))) void*)g,
        (__attribute__((address_space(3))) void*)l, 16, 0, 0);
}

// ---------- fused: fp32->bf16 cvt + stat zeroing + out zeroing + member lists
__global__ __launch_bounds__(256) void cvt_build(const float* __restrict__ in,
                                                 unsigned short* __restrict__ out,
                                                 float* __restrict__ statz,   // negsum+negmax
                                                 const int* __restrict__ labels,
                                                 int* __restrict__ members,
                                                 int* __restrict__ classCount,
                                                 float* __restrict__ loss_out,
                                                 int n4, int nz4, int ncvt, int Bn) {
    __shared__ int cnt;
    const int bid = blockIdx.x;
    const int t = threadIdx.x;
    if (bid < ncvt) {
        int i = bid * 256 + t;
        if (bid == 0 && t == 0) loss_out[0] = 0.0f;
        if (i < nz4) ((float4*)statz)[i] = make_float4(0.f, 0.f, 0.f, 0.f);
        if (i >= n4) return;
        float4 v = ((const float4*)in)[i];
        ushort4 o;
        o.x = f2bf(v.x); o.y = f2bf(v.y); o.z = f2bf(v.z); o.w = f2bf(v.w);
        ((ushort4*)out)[i] = o;
    } else {
        const int c = bid - ncvt;
        if (t == 0) cnt = 0;
        __syncthreads();
        for (int j = t; j < Bn; j += 256) {
            if (labels[j] == c) {
                int p = atomicAdd(&cnt, 1);
                if (p < MEMSTRIDE) members[c * MEMSTRIDE + p] = j;
            }
        }
        __syncthreads();
        if (t == 0) classCount[c] = (cnt < MEMSTRIDE) ? cnt : MEMSTRIDE;
    }
}

// ---------- GEMM (lower-tri tiles) + fused neg stats + pos scatter ----------
// 128x128 tile, BK=32, TRIPLE-buffered global_load_lds with raw
// `s_waitcnt vmcnt(4); s_barrier` per stage (AITER-style: never drain to 0).
// DMA for stage s+2 issued at stage s -> ~2 compute stages of latency cover.
// Barrier safety: buf (s+2)%3 was last read in compute(s-1), which precedes
// every wave's stage-s barrier. Diag tiles stage B redundantly so vmcnt
// counts stay wave-uniform.
__global__ __launch_bounds__(256) void gemm_fused(const unsigned short* __restrict__ fb,
                                                  const int* __restrict__ labels,
                                                  float* __restrict__ negsum,
                                                  unsigned* __restrict__ negmax,
                                                  unsigned short* __restrict__ pairsim,
                                                  int Bn, int Dn) {
    __shared__ __align__(16) unsigned short As[3][4096];   // 24KB
    __shared__ __align__(16) unsigned short Bs[3][4096];   // 24KB
    __shared__ int Lrow[128], Lcol[128];

    const int bid = blockIdx.x;
    int by = (int)((sqrtf(8.f * (float)bid + 1.f) - 1.f) * 0.5f);
    while ((by + 1) * (by + 2) / 2 <= bid) by++;
    while (by * (by + 1) / 2 > bid) by--;
    const int bx = bid - by * (by + 1) / 2;
    const bool diag = (bx == by);

    const int t = threadIdx.x;
    const int wave = t >> 6, lane = t & 63;
    const int wr = wave >> 1, wc = wave & 1;
    const int quad = lane >> 4, m16 = lane & 15;

    if (t < 128) Lrow[t] = labels[by * 128 + t];
    else         Lcol[t - 128] = labels[bx * 128 + (t - 128)];

    // staging: thread t -> LDS offset t*16B (rows lr, lr+64), k-chunk rotated.
    const int lr = t >> 2, slot = t & 3, kf = (slot + lr) & 3;
    const unsigned short* gA0 = fb + (size_t)(by * 128 + lr) * Dn + kf * 8;
    const unsigned short* gB0 = fb + (size_t)(bx * 128 + lr) * Dn + kf * 8;
    const unsigned short* gA1 = gA0 + (size_t)64 * Dn;
    const unsigned short* gB1 = gB0 + (size_t)64 * Dn;
    const int lb = t * 8;   // shorts

    floatx4 acc[4][4];
#pragma unroll
    for (int i = 0; i < 4; i++)
#pragma unroll
        for (int j = 0; j < 4; j++) acc[i][j] = (floatx4){0.f, 0.f, 0.f, 0.f};

    // fragment reads: row stride 32 shorts; chunk quad at slot (quad-m16)&3
    const int fragA = (wr * 64 + m16) * 32 + ((quad - m16) & 3) * 8;
    const int fragB = (wc * 64 + m16) * 32 + ((quad - m16) & 3) * 8;

    const int NS = Dn / 32;   // 32 stages

    __syncthreads();          // Lrow/Lcol visible (full drain, one-time)

    // prologue: stages 0,1 into bufs 0,1 (4 DMAs each, uniform incl. diag)
    gld16(gA0, &As[0][lb]);
    gld16(gA1, &As[0][2048 + lb]);
    gld16(gB0, &Bs[0][lb]);
    gld16(gB1, &Bs[0][2048 + lb]);
    gld16(gA0 + 32, &As[1][lb]);
    gld16(gA1 + 32, &As[1][2048 + lb]);
    gld16(gB0 + 32, &Bs[1][lb]);
    gld16(gB1 + 32, &Bs[1][2048 + lb]);

    int b = 0, b2 = 2;        // b = s%3, b2 = (s+2)%3
    for (int s = 0; s < NS; s++) {
        // wait for DMA(s) (leave DMA(s+1)'s 4 loads in flight), then barrier
        if (s == NS - 1) {
            asm volatile("s_waitcnt vmcnt(0)\n\ts_barrier" ::: "memory");
        } else {
            asm volatile("s_waitcnt vmcnt(4)\n\ts_barrier" ::: "memory");
        }
        // issue DMA(s+2) into buf b2 (safe: compute(s-1) done on all waves)
        if (s + 2 < NS) {
            const int ko = (s + 2) * 32;
            gld16(gA0 + ko, &As[b2][lb]);
            gld16(gA1 + ko, &As[b2][2048 + lb]);
            gld16(gB0 + ko, &Bs[b2][lb]);
            gld16(gB1 + ko, &Bs[b2][2048 + lb]);
        }
        __builtin_amdgcn_sched_barrier(0);   // pin DMA issue before compute

        const unsigned short* as_ = &As[b][0];
        const unsigned short* bs_ = &Bs[b][0];
        short8 af[4], bfr[4];
#pragma unroll
        for (int i = 0; i < 4; i++) af[i]  = *(const short8*)(as_ + fragA + i * 512);
#pragma unroll
        for (int i = 0; i < 4; i++) bfr[i] = *(const short8*)(bs_ + fragB + i * 512);
#pragma unroll
        for (int i = 0; i < 4; i++)
#pragma unroll
            for (int j = 0; j < 4; j++)
                acc[i][j] = __builtin_amdgcn_mfma_f32_16x16x32_bf16(af[i], bfr[j], acc[i][j], 0, 0, 0);

        b++;  if (b == 3)  b = 0;
        b2++; if (b2 == 3) b2 = 0;
    }

    // ----- single-pass epilogue (C/D: col = m16 + j*16, row = quad*4+r + i*16)
    const bool offd = !diag;
    int cl[4], gc[4];
#pragma unroll
    for (int j = 0; j < 4; j++) {
        cl[j] = Lcol[wc * 64 + j * 16 + m16];
        gc[j] = bx * 128 + wc * 64 + j * 16 + m16;
    }

    float nsm[4] = {0.f, 0.f, 0.f, 0.f};
    float nmm[4] = {-INFINITY, -INFINITY, -INFINITY, -INFINITY};

#pragma unroll
    for (int i = 0; i < 4; i++) {
#pragma unroll
        for (int r = 0; r < 4; r++) {
            const int rowl = wr * 64 + i * 16 + quad * 4 + r;
            const int rl = Lrow[rowl];
            const int gr = by * 128 + rowl;
            float ns = 0.f, nm = -INFINITY;
#pragma unroll
            for (int j = 0; j < 4; j++) {
                const float s = acc[i][j][r];
                if (cl[j] != rl) {
                    const float e = __expf(40.f * s);
                    ns += e;
                    nm = fmaxf(nm, s);
                    nsm[j] += e;
                    nmm[j] = fmaxf(nmm[j], s);
                } else if ((gr != gc[j]) & (s < ONE_M_EPS)) {
                    const unsigned short v = f2bf(s);
                    pairsim[(size_t)gr * Bn + gc[j]] = v;
                    if (offd) pairsim[(size_t)gc[j] * Bn + gr] = v;
                }
            }
#pragma unroll
            for (int o = 8; o; o >>= 1) {
                ns += __shfl_down(ns, o, 64);
                nm = fmaxf(nm, __shfl_down(nm, o, 64));
            }
            if (m16 == 0) {
                atomicAdd(negsum + gr, ns);
                atomicMax(negmax + gr, fkey(nm));
            }
        }
    }
    if (offd) {   // mirror negative stats: this tile's cols are rows bx*128..
#pragma unroll
        for (int j = 0; j < 4; j++) {
            float v = nsm[j], m = nmm[j];
            v += __shfl_down(v, 16, 64);
            m = fmaxf(m, __shfl_down(m, 16, 64));
            v += __shfl_down(v, 32, 64);
            m = fmaxf(m, __shfl_down(m, 32, 64));
            if (quad == 0) {
                atomicAdd(negsum + gc[j], v);
                atomicMax(negmax + gc[j], fkey(m));
            }
        }
    }
}

// ---------- positives + per-row loss + mean, merged (16 rows/block) ---------
__global__ __launch_bounds__(256) void pos_final(const unsigned short* __restrict__ pairsim,
                                                 const int* __restrict__ labels,
                                                 const int* __restrict__ members,
                                                 const int* __restrict__ classCount,
                                                 const unsigned* __restrict__ negmax,
                                                 const float* __restrict__ negsum,
                                                 float* __restrict__ out, int Bn) {
    __shared__ float part[4];
    const int t = threadIdx.x;
    const int wave = t >> 6, lane = t & 63;
    float wacc = 0.f;
#pragma unroll
    for (int rr = 0; rr < 4; rr++) {
        const int r = blockIdx.x * 16 + wave * 4 + rr;
        if (r >= Bn) break;
        const int lab = labels[r];
        const int n = classCount[lab];
        const int base = lab * MEMSTRIDE;
        const float mx = fdec(negmax[r]);
        const unsigned short* prow = pairsim + (size_t)r * Bn;

        float ps = 0.f, pc = 0.f;
        for (int j = lane; j < n; j += 64) {
            const int m = members[base + j];
            if (m != r) {
                const float s = bf2f(prow[m]);
                if ((s - MARGIN_C) < mx) {
                    ps += __expf(-2.f * s);
                    pc += 1.f;
                }
            }
        }
#pragma unroll
        for (int o = 32; o; o >>= 1) {
            ps += __shfl_down(ps, o, 64);
            pc += __shfl_down(pc, o, 64);
        }
        if (lane == 0) {
            const int nneg = Bn - n;
            if (nneg >= 1 && pc >= 0.5f) {
                float pl = 0.5f * logf((ps + expf(-2.f * 0.501f)) / (pc + 1.f));
                float nl = (1.f / 40.f) * logf((negsum[r] + expf(40.f * 0.531f)) / ((float)nneg + 1.f));
                wacc += logf(5.33f + expf(pl + nl));
            }
        }
    }
    if (lane == 0) part[wave] = wacc;
    __syncthreads();
    if (t == 0) {
        atomicAdd(out, (part[0] + part[1] + part[2] + part[3]) / (float)Bn);
    }
}

extern "C" void kernel_launch(void* const* d_in, const int* in_sizes, int n_in,
                              void* d_out, int out_size, void* d_ws, size_t ws_size,
                              hipStream_t stream) {
    const float* feats = (const float*)d_in[0];
    const int* labels  = (const int*)d_in[1];
    float* out = (float*)d_out;

    const int Bn = in_sizes[1];           // 4096
    const int Dn = in_sizes[0] / Bn;      // 1024

    unsigned short* fb = (unsigned short*)d_ws;                 // bf16 feats [Bn][Dn]
    float* stats    = (float*)(fb + (size_t)Bn * Dn);
    float* negsum   = stats;                                    // [Bn]
    unsigned* negmax = (unsigned*)(stats + Bn);                 // [Bn] keyed
    int* classCount = (int*)(stats + 2 * Bn);                   // [NCLS]
    int* members    = classCount + NCLS;                        // [NCLS][MEMSTRIDE]
    unsigned short* pairsim = (unsigned short*)(members + NCLS * MEMSTRIDE); // [Bn][Bn]

    const int n4   = (Bn * Dn) / 4;
    const int nz4  = (2 * Bn) / 4;        // zero negsum+negmax
    const int ncvt = (n4 + 255) / 256;
    cvt_build<<<ncvt + NCLS, 256, 0, stream>>>(feats, fb, stats, labels,
                                               members, classCount, out,
                                               n4, nz4, ncvt, Bn);

    const int nt = Bn / 128;
    const int ntri = nt * (nt + 1) / 2;   // 528
    gemm_fused<<<ntri, 256, 0, stream>>>(fb, labels, negsum, negmax, pairsim, Bn, Dn);

    pos_final<<<(Bn + 15) / 16, 256, 0, stream>>>(pairsim, labels, members, classCount,
                                                  negmax, negsum, out, Bn);
}